// Round 1
// baseline (91.203 us; speedup 1.0000x reference)
//
#include <hip/hip_runtime.h>

// Problem dims (from setup_inputs): vol [2,160,192,160,1] f32, trf [2,160,192,160,3] f32
constexpr int B = 2, X = 160, Y = 192, Z = 160;
constexpr int N = B * X * Y * Z;   // 9,830,400

__global__ __launch_bounds__(256) void warp_kernel(
    const float* __restrict__ vol,
    const float* __restrict__ trf,
    float* __restrict__ out)
{
    int idx = blockIdx.x * blockDim.x + threadIdx.x;
    if (idx >= N) return;

    // decompose idx -> (b, x, y, z), row-major with z innermost
    int z  = idx % Z;
    int t  = idx / Z;
    int y  = t % Y;
    int t2 = t / Y;
    int x  = t2 % X;
    int b  = t2 / X;

    // displacement (interleaved last-dim-3)
    size_t toff = (size_t)idx * 3;
    float dx = trf[toff + 0];
    float dy = trf[toff + 1];
    float dz = trf[toff + 2];

    float lx = (float)x + dx;
    float ly = (float)y + dy;
    float lz = (float)z + dz;

    // per-dim: i0, i1, weight for i0 corner (wA), weight for i1 corner (wB)
    // reference: l0=clip(floor(l),0,max); l1=clip(l0+1,0,max); cl=clip(l,0,max)
    //            wA = l1 - cl (corner bit 0), wB = 1 - wA (corner bit 1)
    float mx = (float)(X - 1), my = (float)(Y - 1), mz = (float)(Z - 1);

    float lx0 = fminf(fmaxf(floorf(lx), 0.0f), mx);
    float lx1 = fminf(lx0 + 1.0f, mx);
    float clx = fminf(fmaxf(lx, 0.0f), mx);
    float wxA = lx1 - clx;
    float wxB = 1.0f - wxA;
    int ix0 = (int)lx0, ix1 = (int)lx1;

    float ly0 = fminf(fmaxf(floorf(ly), 0.0f), my);
    float ly1 = fminf(ly0 + 1.0f, my);
    float cly = fminf(fmaxf(ly, 0.0f), my);
    float wyA = ly1 - cly;
    float wyB = 1.0f - wyA;
    int iy0 = (int)ly0, iy1 = (int)ly1;

    float lz0 = fminf(fmaxf(floorf(lz), 0.0f), mz);
    float lz1 = fminf(lz0 + 1.0f, mz);
    float clz = fminf(fmaxf(lz, 0.0f), mz);
    float wzA = lz1 - clz;
    float wzB = 1.0f - wzA;
    int iz0 = (int)lz0, iz1 = (int)lz1;

    // gather 8 corners: vol index = ((b*X + xi)*Y + yi)*Z + zi
    const float* volb = vol;
    int bX = b * X;
    size_t base00 = ((size_t)(bX + ix0) * Y + iy0) * Z;
    size_t base01 = ((size_t)(bX + ix0) * Y + iy1) * Z;
    size_t base10 = ((size_t)(bX + ix1) * Y + iy0) * Z;
    size_t base11 = ((size_t)(bX + ix1) * Y + iy1) * Z;

    float v000 = volb[base00 + iz0];
    float v001 = volb[base00 + iz1];
    float v010 = volb[base01 + iz0];
    float v011 = volb[base01 + iz1];
    float v100 = volb[base10 + iz0];
    float v101 = volb[base10 + iz1];
    float v110 = volb[base11 + iz0];
    float v111 = volb[base11 + iz1];

    float r = wxA * (wyA * (wzA * v000 + wzB * v001) +
                     wyB * (wzA * v010 + wzB * v011)) +
              wxB * (wyA * (wzA * v100 + wzB * v101) +
                     wyB * (wzA * v110 + wzB * v111));

    out[idx] = r;
}

extern "C" void kernel_launch(void* const* d_in, const int* in_sizes, int n_in,
                              void* d_out, int out_size, void* d_ws, size_t ws_size,
                              hipStream_t stream) {
    const float* vol = (const float*)d_in[0];
    const float* trf = (const float*)d_in[1];
    float* out = (float*)d_out;

    int threads = 256;
    int blocks = (N + threads - 1) / threads;
    warp_kernel<<<blocks, threads, 0, stream>>>(vol, trf, out);
}